// Round 7
// baseline (1816.822 us; speedup 1.0000x reference)
//
#include <hip/hip_runtime.h>

namespace {

constexpr int B = 64;
constexpr int L = 2048;
constexpr int Q = 256;
constexpr int S = 26;
constexpr float EPS = 1e-16f;
constexpr size_t POST = (size_t)B * L * Q;  // loglik offset in d_out

typedef _Float16 h2 __attribute__((ext_vector_type(2)));
typedef _Float16 f16x8 __attribute__((ext_vector_type(8)));
typedef float f32x4 __attribute__((ext_vector_type(4)));

#define MFMA16(a, b, c) __builtin_amdgcn_mfma_f32_16x16x32_f16((a), (b), (c), 0, 0, 0)

// ---------------- shared helpers ----------------

__device__ __forceinline__ void lds_barrier() {
  asm volatile("s_waitcnt lgkmcnt(0)\n\ts_barrier" ::: "memory");
}

__device__ __forceinline__ float wave_max64(float x) {
#pragma unroll
  for (int off = 32; off > 0; off >>= 1) x = fmaxf(x, __shfl_xor(x, off, 64));
  return x;
}
__device__ __forceinline__ float wave_sum64(float x) {
#pragma unroll
  for (int off = 32; off > 0; off >>= 1) x += __shfl_xor(x, off, 64);
  return x;
}

// ======================================================================
// PATH A: emission precomputed to ws as f16; serial loop slimmed.
// ======================================================================

struct SmemE {
  alignas(16) _Float16 vb[2][Q];  // scaled linear recursion vector (f16), dbuf
  float sh[2];                    // state-0 anchor broadcast (f32), dbuf
  alignas(16) float afin[Q];      // final alpha for exact loglik
};

// x = v^T * T, two 16-state tiles; K=256 as 8 frags, 2-deep chains (8
// independent). Only D row 0 (reg 0, lanes 0..15) is meaningful; garbage in
// A rows 1..15 cannot reach row 0.
__device__ __forceinline__ void matvec2(const f16x8* va, const f16x8* T0,
                                        const f16x8* T1, float& x0, float& x1) {
  const f32x4 Z = {0.f, 0.f, 0.f, 0.f};
  f32x4 a0 = MFMA16(va[0], T0[0], Z); a0 = MFMA16(va[1], T0[1], a0);
  f32x4 b0 = MFMA16(va[2], T0[2], Z); b0 = MFMA16(va[3], T0[3], b0);
  f32x4 c0 = MFMA16(va[4], T0[4], Z); c0 = MFMA16(va[5], T0[5], c0);
  f32x4 d0 = MFMA16(va[6], T0[6], Z); d0 = MFMA16(va[7], T0[7], d0);
  f32x4 a1 = MFMA16(va[0], T1[0], Z); a1 = MFMA16(va[1], T1[1], a1);
  f32x4 b1 = MFMA16(va[2], T1[2], Z); b1 = MFMA16(va[3], T1[3], b1);
  f32x4 c1 = MFMA16(va[4], T1[4], Z); c1 = MFMA16(va[5], T1[5], c1);
  f32x4 d1 = MFMA16(va[6], T1[6], Z); d1 = MFMA16(va[7], T1[7], d1);
  x0 = (a0[0] + b0[0]) + (c0[0] + d0[0]);
  x1 = (a1[0] + b1[0]) + (c1[0] + d1[0]);
}

// Sparse vb frag reads: lanes with (lane&15)==0 only (A-row-0 trick).
__device__ __forceinline__ void read_va(SmemE& sm, int p, int g, f16x8* va) {
  const _Float16* vbp = sm.vb[p];
#pragma unroll
  for (int f = 0; f < 8; ++f) va[f] = *(const f16x8*)(vbp + f * 32 + g * 8);
}

// ---- emission precompute: e[b][t][q] = f16(max(dot + EPS, 6e-5)) ----
// A-frag: lane l holds row (l&15), k-elem (l>>4)*8+j (validated implicitly by
// 6 passing rounds of the row-0 matvec trick). D: col=lane&15,
// row=(lane>>4)*4+reg [m89]. Hi/lo f16 split = same numerics as the in-loop
// emission of the verified kernels.
__global__ __launch_bounds__(512)
void hmm_emit(const float* __restrict__ inputs, const float* __restrict__ log_B,
              _Float16* __restrict__ eall) {
  const int tid = threadIdx.x, w = tid >> 6, lane = tid & 63;
  const int g = lane >> 4, q = lane & 15;
  const int b = blockIdx.x >> 2, quar = blockIdx.x & 3;
  const float* __restrict__ inp = inputs + (size_t)b * L * S;
  _Float16* __restrict__ eb = eall + (size_t)b * L * Q;

  const int tbase = (quar * 32 + w * 4) * 16;  // first t-row of this wave
  f16x8 xh[4], xl[4];
#pragma unroll
  for (int i = 0; i < 4; ++i) {
    const int trow = tbase + i * 16 + q;
    const float* rp = inp + (size_t)trow * S;
    float v[8];
#pragma unroll
    for (int j = 0; j < 8; ++j) {
      const int s = g * 8 + j;
      v[j] = (s < S) ? rp[s] : 0.f;
    }
#pragma unroll
    for (int j = 0; j < 8; ++j) {
      const _Float16 h = (_Float16)v[j];
      xh[i][j] = h;
      xl[i][j] = (_Float16)(v[j] - (float)h);
    }
  }
  for (int k = 0; k < 16; ++k) {  // 16 state-tiles of 16
    f16x8 Bh, Bl;
#pragma unroll
    for (int j = 0; j < 8; ++j) {
      const int s = g * 8 + j;
      const float vv = (s < S) ? __expf(log_B[(size_t)(k * 16 + q) * S + s]) : 0.f;
      const _Float16 h = (_Float16)vv;
      Bh[j] = h;
      Bl[j] = (_Float16)(vv - (float)h);
    }
    const f32x4 Z = {0.f, 0.f, 0.f, 0.f};
#pragma unroll
    for (int i = 0; i < 4; ++i) {
      f32x4 E = MFMA16(xh[i], Bl, Z);
      E = MFMA16(xl[i], Bh, E);
      E = MFMA16(xh[i], Bh, E);
      const int t0 = tbase + i * 16 + (lane >> 4) * 4;
      const int col = k * 16 + (lane & 15);
#pragma unroll
      for (int r = 0; r < 4; ++r) {
        const float ev = fmaxf(E[r] + EPS, 6.0e-5f);  // f16-subnormal guard
        eb[(size_t)(t0 + r) * Q + col] = (_Float16)ev;
      }
    }
  }
}

// ---- forward, e from ws. R4 anchor mechanics unchanged. e prefetched 4
// steps ahead via 4 rotating register pairs (unroll-4, self-target, rule #20
// static indexing); vmcnt never drained in-loop (lds_barrier).
__device__ __forceinline__ void fwd_e(int b, const _Float16* __restrict__ eall,
                                      const float* __restrict__ log_A,
                                      const float* __restrict__ log_pi,
                                      float* __restrict__ out, SmemE& sm) {
  const int tid = threadIdx.x, w = tid >> 6, lane = tid & 63;
  const int g = lane >> 4, q = lane & 15;
  const int c0 = w * 32, c1 = c0 + 16;
  const bool rdl = (q == 0);
  const bool epi = (lane < 16);

  f16x8 T0[8], T1[8];  // T[k][c] = exp(log_A[k*Q+c]), persistent VGPRs
#pragma unroll
  for (int f = 0; f < 8; ++f) {
#pragma unroll
    for (int j = 0; j < 8; ++j) {
      const int k = f * 32 + g * 8 + j;
      T0[f][j] = (_Float16)__expf(log_A[(size_t)k * Q + c0 + q]);
      T1[f][j] = (_Float16)__expf(log_A[(size_t)k * Q + c1 + q]);
    }
  }

  const _Float16* __restrict__ eb = eall + (size_t)b * L * Q;
  float* __restrict__ post_b = out + (size_t)b * L * Q;
  const _Float16* e0p = eb + c0 + lane;

  // e prefetch: row 0 immediate; rows 1..4 into pairs 1,2,3,0
  float ez0 = 1.f, ez1 = 1.f;
  float e1a = 1.f, e1b = 1.f, e2a = 1.f, e2b = 1.f;
  float e3a = 1.f, e3b = 1.f, e0a = 1.f, e0b = 1.f;
  if (epi) {
    ez0 = (float)e0p[0];        ez1 = (float)e0p[16];
    e1a = (float)e0p[1 * Q];    e1b = (float)e0p[1 * Q + 16];
    e2a = (float)e0p[2 * Q];    e2b = (float)e0p[2 * Q + 16];
    e3a = (float)e0p[3 * Q];    e3b = (float)e0p[3 * Q + 16];
    e0a = (float)e0p[4 * Q];    e0b = (float)e0p[4 * Q + 16];
  }

  // t = 0
  float zh0 = 1.f, zh1 = 1.f, rdp_h = 0.f;
  if (epi) {
    zh0 = ez0 * __expf(log_pi[c0 + lane]);
    zh1 = ez1 * __expf(log_pi[c1 + lane]);
  }
  if (tid == 0) sm.sh[0] = __logf(zh0);  // alpha_0(0)
  __syncthreads();
  float rd_prev = sm.sh[0];
  if (epi) {
    const float sc = __expf(-rd_prev);
    sm.vb[0][c0 + lane] = (_Float16)(zh0 * sc);
    sm.vb[0][c1 + lane] = (_Float16)(zh1 * sc);
  }
  __syncthreads();

  f16x8 va[8];
#pragma unroll
  for (int f = 0; f < 8; ++f) va[f] = f16x8{};

  const _Float16* ep = eb + (size_t)5 * Q + c0 + lane;        // row t+4 at t=1
  const _Float16* epLast = eb + (size_t)(L - 1) * Q + c0 + lane;
  float* pb = post_b + c0 + lane;
  int p = 0;

  auto step = [&](float& eX0, float& eX1) {
    const float rd = sm.sh[p];          // alpha_{t-1}(0)
    if (rdl) read_va(sm, p, g, va);     // 8 ds_read_b128 (4 lanes)
    if (epi) {                          // delayed alpha_{t-1} store
      pb[0] = __logf(zh0) + rdp_h;
      pb[16] = __logf(zh1) + rdp_h;
    }
    pb += Q;
    float x0, x1;
    matvec2(va, T0, T1, x0, x1);
    const float gam = __expf(rd_prev - rd);
    if (epi) {
      const float z0 = x0 * eX0, z1 = x1 * eX1;
      sm.vb[p ^ 1][c0 + lane] = (_Float16)(z0 * gam);
      sm.vb[p ^ 1][c1 + lane] = (_Float16)(z1 * gam);
      if (tid == 0) sm.sh[p ^ 1] = __logf(z0) + rd_prev;  // alpha_t(0)
      zh0 = z0; zh1 = z1;
      const _Float16* pe = (ep <= epLast) ? ep : epLast;   // row t+4 (clamped)
      eX0 = (float)pe[0];
      eX1 = (float)pe[16];
    }
    ep += Q;
    rdp_h = rd_prev;
    rd_prev = rd;
    lds_barrier();
    p ^= 1;
  };

  int t = 1;
  for (; t + 3 < L; t += 4) {  // 511 groups, t=1..2044
    step(e1a, e1b);
    step(e2a, e2b);
    step(e3a, e3b);
    step(e0a, e0b);
  }
  step(e1a, e1b);  // t=2045
  step(e2a, e2b);  // t=2046
  step(e3a, e3b);  // t=2047

  // epilogue: final alpha store + exact loglik
  if (epi) {
    const float a0 = __logf(zh0) + rdp_h;
    const float a1 = __logf(zh1) + rdp_h;
    pb[0] = a0; pb[16] = a1;
    sm.afin[c0 + lane] = a0;
    sm.afin[c1 + lane] = a1;
  }
  __syncthreads();
  if (w == 0) {
    float4 fa = ((const float4*)sm.afin)[lane];
    float m = fmaxf(fmaxf(fa.x, fa.y), fmaxf(fa.z, fa.w));
    m = wave_max64(m);
    float ss = __expf(fa.x - m) + __expf(fa.y - m) + __expf(fa.z - m) + __expf(fa.w - m);
    ss = wave_sum64(ss);
    if (lane == 0) out[POST + b] = __logf(ss) + m;
  }
}

// ---- backward, e from ws, beta -> ws (MODE0-style) ----
__device__ __forceinline__ void bwd_e(int b, const _Float16* __restrict__ eall,
                                      const float* __restrict__ log_A,
                                      float* __restrict__ ws, SmemE& sm) {
  const int tid = threadIdx.x, w = tid >> 6, lane = tid & 63;
  const int g = lane >> 4, q = lane & 15;
  const int c0 = w * 32, c1 = c0 + 16;
  const bool rdl = (q == 0);
  const bool epi = (lane < 16);

  f16x8 T0[8], T1[8];  // bwd: T[k][c] = exp(log_A[c*Q + k])
#pragma unroll
  for (int f = 0; f < 8; ++f) {
#pragma unroll
    for (int j = 0; j < 8; ++j) {
      const int k = f * 32 + g * 8 + j;
      T0[f][j] = (_Float16)__expf(log_A[(size_t)(c0 + q) * Q + k]);
      T1[f][j] = (_Float16)__expf(log_A[(size_t)(c1 + q) * Q + k]);
    }
  }

  const _Float16* __restrict__ eb = eall + (size_t)b * L * Q;
  float* __restrict__ ws_b = ws + (size_t)b * L * Q;
  const _Float16* eLp = eb + (size_t)(L - 1) * Q + c0 + lane;

  // e prefetch: row L-1 immediate; rows L-2..L-5 into pairs 1,2,3,0
  float ez0 = 1.f, ez1 = 1.f;
  float e1a = 1.f, e1b = 1.f, e2a = 1.f, e2b = 1.f;
  float e3a = 1.f, e3b = 1.f, e0a = 1.f, e0b = 1.f;
  if (epi) {
    ez0 = (float)eLp[0];            ez1 = (float)eLp[16];
    e1a = (float)eLp[-1 * Q];       e1b = (float)eLp[-1 * Q + 16];
    e2a = (float)eLp[-2 * Q];       e2b = (float)eLp[-2 * Q + 16];
    e3a = (float)eLp[-3 * Q];       e3b = (float)eLp[-3 * Q + 16];
    e0a = (float)eLp[-4 * Q];       e0b = (float)eLp[-4 * Q + 16];
  }

  // t = L-1
  if (tid == 0) sm.sh[0] = __logf(ez0);  // u_{L-1}(0)
  __syncthreads();
  float rd_prev = sm.sh[0];
  if (epi) {
    const float sc = __expf(-rd_prev);
    sm.vb[0][c0 + lane] = (_Float16)(ez0 * sc);
    sm.vb[0][c1 + lane] = (_Float16)(ez1 * sc);
  }
  float rh0 = 1.f, rh1 = 1.f, rdp_h = 0.f;  // beta_{L-1} = 0
  __syncthreads();

  f16x8 va[8];
#pragma unroll
  for (int f = 0; f < 8; ++f) va[f] = f16x8{};

  const _Float16* ep = eb + (size_t)(L - 6) * Q + c0 + lane;  // row t-4 at t=L-2
  const _Float16* epFirst = eb + c0 + lane;
  float* wp = ws_b + (size_t)(L - 1) * Q + c0 + lane;
  int p = 0;

  auto step = [&](float& eX0, float& eX1) {
    const float rd = sm.sh[p];
    if (rdl) read_va(sm, p, g, va);
    if (epi) {  // delayed beta_{t+1} store
      wp[0] = __logf(rh0) + rdp_h;
      wp[16] = __logf(rh1) + rdp_h;
    }
    wp -= Q;
    float x0, x1;
    matvec2(va, T0, T1, x0, x1);
    const float gam = __expf(rd_prev - rd);
    if (epi) {
      const float z0 = x0 * eX0, z1 = x1 * eX1;
      sm.vb[p ^ 1][c0 + lane] = (_Float16)(z0 * gam);
      sm.vb[p ^ 1][c1 + lane] = (_Float16)(z1 * gam);
      if (tid == 0) sm.sh[p ^ 1] = __logf(z0) + rd_prev;  // u_t(0)
      rh0 = x0; rh1 = x1;
      const _Float16* pe = (ep >= epFirst) ? ep : epFirst;  // row t-4 (clamped)
      eX0 = (float)pe[0];
      eX1 = (float)pe[16];
    }
    ep -= Q;
    rdp_h = rd_prev;
    rd_prev = rd;
    lds_barrier();
    p ^= 1;
  };

  int t = L - 2;
  for (; t >= 3; t -= 4) {  // 511 groups, t=2046..3
    step(e1a, e1b);
    step(e2a, e2b);
    step(e3a, e3b);
    step(e0a, e0b);
  }
  step(e1a, e1b);  // t=2
  step(e2a, e2b);  // t=1
  step(e3a, e3b);  // t=0

  // epilogue: beta row 0
  if (epi) {
    wp[0] = __logf(rh0) + rdp_h;
    wp[16] = __logf(rh1) + rdp_h;
  }
}

__global__ __launch_bounds__(512, 2)
void hmm_fwdbwd_e(const _Float16* __restrict__ eall, const float* __restrict__ log_A,
                  const float* __restrict__ log_pi, float* __restrict__ out,
                  float* __restrict__ ws) {
  __shared__ SmemE sm;
  if (blockIdx.x < B) fwd_e(blockIdx.x, eall, log_A, log_pi, out, sm);
  else                bwd_e(blockIdx.x - B, eall, log_A, ws, sm);
}

// ======================================================================
// PATH B / fallback: verbatim R4 kernels (known-good, 1470 us).
// ======================================================================

struct Smem {
  alignas(16) _Float16 vb[2][Q];
  alignas(16) _Float16 rowh[2][32];
  alignas(16) _Float16 rowl[2][32];
  float sh[2];
  alignas(16) float afin[Q];
};

__device__ __forceinline__ void load_emit_frags(const float* __restrict__ log_B,
                                                int c0, int c1, int g, int q,
                                                f16x8& Bh0, f16x8& Bl0,
                                                f16x8& Bh1, f16x8& Bl1) {
#pragma unroll
  for (int j = 0; j < 8; ++j) {
    const int s = g * 8 + j;
    const float v0 = (s < S) ? __expf(log_B[(size_t)(c0 + q) * S + s]) : 0.f;
    const float v1 = (s < S) ? __expf(log_B[(size_t)(c1 + q) * S + s]) : 0.f;
    const _Float16 h0 = (_Float16)v0, h1 = (_Float16)v1;
    Bh0[j] = h0; Bl0[j] = (_Float16)(v0 - (float)h0);
    Bh1[j] = h1; Bl1[j] = (_Float16)(v1 - (float)h1);
  }
}

__device__ __forceinline__ void stage_row(Smem& sm, int buf, int lane, float2 gg) {
  _Float16 ah = (_Float16)0.f, bh = (_Float16)0.f;
  _Float16 al = (_Float16)0.f, bl = (_Float16)0.f;
  if (lane < 13) {
    ah = (_Float16)gg.x; bh = (_Float16)gg.y;
    al = (_Float16)(gg.x - (float)ah);
    bl = (_Float16)(gg.y - (float)bh);
  }
  ((h2*)sm.rowh[buf])[lane] = h2{ah, bh};
  ((h2*)sm.rowl[buf])[lane] = h2{al, bl};
}

__device__ __forceinline__ void emit_mfma(const f16x8& xh, const f16x8& xl,
                                          const f16x8& Bh0, const f16x8& Bl0,
                                          const f16x8& Bh1, const f16x8& Bl1,
                                          f32x4& E0, f32x4& E1) {
  const f32x4 Z = {0.f, 0.f, 0.f, 0.f};
  E0 = MFMA16(xh, Bl0, Z);
  E0 = MFMA16(xl, Bh0, E0);
  E0 = MFMA16(xh, Bh0, E0);
  E1 = MFMA16(xh, Bl1, Z);
  E1 = MFMA16(xl, Bh1, E1);
  E1 = MFMA16(xh, Bh1, E1);
}

__device__ __forceinline__ void matvec_mfma(const f16x8* va, const f16x8* T0,
                                            const f16x8* T1, float& x0, float& x1) {
  const f32x4 Z = {0.f, 0.f, 0.f, 0.f};
  f32x4 X0a = MFMA16(va[0], T0[0], Z);
  f32x4 X1a = MFMA16(va[0], T1[0], Z);
  f32x4 X0b = MFMA16(va[4], T0[4], Z);
  f32x4 X1b = MFMA16(va[4], T1[4], Z);
#pragma unroll
  for (int f = 1; f < 4; ++f) {
    X0a = MFMA16(va[f], T0[f], X0a);
    X1a = MFMA16(va[f], T1[f], X1a);
    X0b = MFMA16(va[f + 4], T0[f + 4], X0b);
    X1b = MFMA16(va[f + 4], T1[f + 4], X1b);
  }
  x0 = X0a[0] + X0b[0];
  x1 = X1a[0] + X1b[0];
}

__device__ __forceinline__ void read_frags(Smem& sm, int p, int g,
                                           f16x8& xh, f16x8& xl, f16x8* va) {
  xh = *(const f16x8*)(sm.rowh[p] + g * 8);
  xl = *(const f16x8*)(sm.rowl[p] + g * 8);
  const _Float16* vbp = sm.vb[p];
#pragma unroll
  for (int f = 0; f < 8; ++f) va[f] = *(const f16x8*)(vbp + f * 32 + g * 8);
}

__device__ __forceinline__ void fwd_impl(int b, const float* __restrict__ inputs,
                                         const float* __restrict__ log_A,
                                         const float* __restrict__ log_pi,
                                         const float* __restrict__ log_B,
                                         float* __restrict__ out, Smem& sm) {
  const int tid = threadIdx.x, w = tid >> 6, lane = tid & 63;
  const int g = lane >> 4, q = lane & 15;
  const int c0 = w * 32, c1 = c0 + 16;
  const bool rdl = (q == 0);
  const bool epi = (lane < 16);
  const bool stg = (w == 0) && (lane < 16);

  f16x8 T0[8], T1[8];
#pragma unroll
  for (int f = 0; f < 8; ++f) {
#pragma unroll
    for (int j = 0; j < 8; ++j) {
      const int k = f * 32 + g * 8 + j;
      T0[f][j] = (_Float16)__expf(log_A[(size_t)k * Q + c0 + q]);
      T1[f][j] = (_Float16)__expf(log_A[(size_t)k * Q + c1 + q]);
    }
  }
  f16x8 Bh0, Bl0, Bh1, Bl1;
  load_emit_frags(log_B, c0, c1, g, q, Bh0, Bl0, Bh1, Bl1);

  const float2* __restrict__ inp2 = (const float2*)(inputs + (size_t)b * L * S);
  float* __restrict__ post_b = out + (size_t)b * L * Q;

  float2 gHold = {0.f, 0.f};
  if (stg) {
    float2 g0 = {0.f, 0.f}, g1 = {0.f, 0.f};
    if (lane < 13) {
      g0 = inp2[lane];
      g1 = inp2[13 + lane];
      gHold = inp2[26 + lane];
    }
    stage_row(sm, 1, lane, g0);
    stage_row(sm, 0, lane, g1);
  }
  __syncthreads();

  f16x8 xh = {}, xl = {};
  f16x8 va[8];
#pragma unroll
  for (int f = 0; f < 8; ++f) va[f] = f16x8{};

  if (rdl) {
    xh = *(const f16x8*)(sm.rowh[1] + g * 8);
    xl = *(const f16x8*)(sm.rowl[1] + g * 8);
  }
  f32x4 E0, E1;
  emit_mfma(xh, xl, Bh0, Bl0, Bh1, Bl1, E0, E1);
  float zh0 = 1.f, zh1 = 1.f, rdp_h = 0.f;
  if (epi) {
    zh0 = (E0[0] + EPS) * __expf(log_pi[c0 + lane]);
    zh1 = (E1[0] + EPS) * __expf(log_pi[c1 + lane]);
  }
  if (tid == 0) sm.sh[0] = __logf(zh0);
  __syncthreads();
  float rd_prev = sm.sh[0];
  if (epi) {
    const float sc = __expf(-rd_prev);
    sm.vb[0][c0 + lane] = (_Float16)(zh0 * sc);
    sm.vb[0][c1 + lane] = (_Float16)(zh1 * sc);
  }
  __syncthreads();

  int p = 0;
  for (int t = 1; t < L; ++t) {
    if (stg) stage_row(sm, p ^ 1, lane, gHold);
    const float rd = sm.sh[p];
    float2 gN = gHold;
    const int tt = (t + 2 < L) ? t + 2 : L - 1;
    if (w == 0 && lane < 13) gN = inp2[(size_t)tt * 13 + lane];
    if (epi) {
      const float a0 = __logf(zh0) + rdp_h;
      const float a1 = __logf(zh1) + rdp_h;
      post_b[(size_t)(t - 1) * Q + c0 + lane] = a0;
      post_b[(size_t)(t - 1) * Q + c1 + lane] = a1;
    }
    if (rdl) read_frags(sm, p, g, xh, xl, va);
    f32x4 E0_, E1_;
    emit_mfma(xh, xl, Bh0, Bl0, Bh1, Bl1, E0_, E1_);
    float x0, x1;
    matvec_mfma(va, T0, T1, x0, x1);
    const float gam = __expf(rd_prev - rd);
    if (epi) {
      const float e0 = E0_[0] + EPS, e1 = E1_[0] + EPS;
      const float z0 = x0 * e0, z1 = x1 * e1;
      sm.vb[p ^ 1][c0 + lane] = (_Float16)(z0 * gam);
      sm.vb[p ^ 1][c1 + lane] = (_Float16)(z1 * gam);
      if (tid == 0) sm.sh[p ^ 1] = __logf(z0) + rd_prev;
      zh0 = z0; zh1 = z1;
    }
    gHold = gN;
    rdp_h = rd_prev;
    rd_prev = rd;
    lds_barrier();
    p ^= 1;
  }

  if (epi) {
    const float a0 = __logf(zh0) + rdp_h;
    const float a1 = __logf(zh1) + rdp_h;
    post_b[(size_t)(L - 1) * Q + c0 + lane] = a0;
    post_b[(size_t)(L - 1) * Q + c1 + lane] = a1;
    sm.afin[c0 + lane] = a0;
    sm.afin[c1 + lane] = a1;
  }
  __syncthreads();
  if (w == 0) {
    float4 fa = ((const float4*)sm.afin)[lane];
    float m = fmaxf(fmaxf(fa.x, fa.y), fmaxf(fa.z, fa.w));
    m = wave_max64(m);
    float ss = __expf(fa.x - m) + __expf(fa.y - m) + __expf(fa.z - m) + __expf(fa.w - m);
    ss = wave_sum64(ss);
    if (lane == 0) out[POST + b] = __logf(ss) + m;
  }
}

template <int MODE>
__device__ __forceinline__ void bwd_impl(int b, const float* __restrict__ inputs,
                                         const float* __restrict__ log_A,
                                         const float* __restrict__ log_B,
                                         float* __restrict__ out,
                                         float* __restrict__ ws, Smem& sm) {
  const int tid = threadIdx.x, w = tid >> 6, lane = tid & 63;
  const int g = lane >> 4, q = lane & 15;
  const int c0 = w * 32, c1 = c0 + 16;
  const bool rdl = (q == 0);
  const bool epi = (lane < 16);
  const bool stg = (w == 0) && (lane < 16);

  f16x8 T0[8], T1[8];
#pragma unroll
  for (int f = 0; f < 8; ++f) {
#pragma unroll
    for (int j = 0; j < 8; ++j) {
      const int k = f * 32 + g * 8 + j;
      T0[f][j] = (_Float16)__expf(log_A[(size_t)(c0 + q) * Q + k]);
      T1[f][j] = (_Float16)__expf(log_A[(size_t)(c1 + q) * Q + k]);
    }
  }
  f16x8 Bh0, Bl0, Bh1, Bl1;
  load_emit_frags(log_B, c0, c1, g, q, Bh0, Bl0, Bh1, Bl1);

  const float2* __restrict__ inp2 = (const float2*)(inputs + (size_t)b * L * S);
  float* __restrict__ post_b = out + (size_t)b * L * Q;
  float* __restrict__ ws_b = ws + (size_t)b * L * Q;

  float ll = 0.f, a_h0 = 0.f, a_h1 = 0.f;
  if (MODE == 1) {
    ll = out[POST + b];
    if (epi) {
      a_h0 = post_b[(size_t)(L - 1) * Q + c0 + lane];
      a_h1 = post_b[(size_t)(L - 1) * Q + c1 + lane];
    }
  }

  float2 gHold = {0.f, 0.f};
  if (stg) {
    float2 g0 = {0.f, 0.f}, g1 = {0.f, 0.f};
    if (lane < 13) {
      g0 = inp2[(size_t)(L - 1) * 13 + lane];
      g1 = inp2[(size_t)(L - 2) * 13 + lane];
      gHold = inp2[(size_t)(L - 3) * 13 + lane];
    }
    stage_row(sm, 1, lane, g0);
    stage_row(sm, 0, lane, g1);
  }
  __syncthreads();

  f16x8 xh = {}, xl = {};
  f16x8 va[8];
#pragma unroll
  for (int f = 0; f < 8; ++f) va[f] = f16x8{};

  if (rdl) {
    xh = *(const f16x8*)(sm.rowh[1] + g * 8);
    xl = *(const f16x8*)(sm.rowl[1] + g * 8);
  }
  f32x4 E0, E1;
  emit_mfma(xh, xl, Bh0, Bl0, Bh1, Bl1, E0, E1);
  float e0i = 1.f, e1i = 1.f;
  if (epi) { e0i = E0[0] + EPS; e1i = E1[0] + EPS; }
  if (tid == 0) sm.sh[0] = __logf(e0i);
  __syncthreads();
  float rd_prev = sm.sh[0];
  if (epi) {
    const float sc = __expf(-rd_prev);
    sm.vb[0][c0 + lane] = (_Float16)(e0i * sc);
    sm.vb[0][c1 + lane] = (_Float16)(e1i * sc);
  }
  float rh0 = 1.f, rh1 = 1.f, rdp_h = 0.f;
  __syncthreads();

  int p = 0;
  for (int t = L - 2; t >= 0; --t) {
    if (stg) stage_row(sm, p ^ 1, lane, gHold);
    const float rd = sm.sh[p];
    float2 gN = gHold;
    const int tt = (t >= 2) ? t - 2 : 0;
    if (w == 0 && lane < 13) gN = inp2[(size_t)tt * 13 + lane];
    if (epi) {
      const float b0 = __logf(rh0) + rdp_h;
      const float b1 = __logf(rh1) + rdp_h;
      if (MODE == 0) {
        ws_b[(size_t)(t + 1) * Q + c0 + lane] = b0;
        ws_b[(size_t)(t + 1) * Q + c1 + lane] = b1;
      } else {
        post_b[(size_t)(t + 1) * Q + c0 + lane] = a_h0 + b0 - ll;
        post_b[(size_t)(t + 1) * Q + c1 + lane] = a_h1 + b1 - ll;
        a_h0 = post_b[(size_t)t * Q + c0 + lane];
        a_h1 = post_b[(size_t)t * Q + c1 + lane];
      }
    }
    if (rdl) read_frags(sm, p, g, xh, xl, va);
    f32x4 E0_, E1_;
    emit_mfma(xh, xl, Bh0, Bl0, Bh1, Bl1, E0_, E1_);
    float r0, r1;
    matvec_mfma(va, T0, T1, r0, r1);
    const float gam = __expf(rd_prev - rd);
    if (epi) {
      const float e0 = E0_[0] + EPS, e1 = E1_[0] + EPS;
      const float z0 = r0 * e0, z1 = r1 * e1;
      sm.vb[p ^ 1][c0 + lane] = (_Float16)(z0 * gam);
      sm.vb[p ^ 1][c1 + lane] = (_Float16)(z1 * gam);
      if (tid == 0) sm.sh[p ^ 1] = __logf(z0) + rd_prev;
      rh0 = r0; rh1 = r1;
    }
    gHold = gN;
    rdp_h = rd_prev;
    rd_prev = rd;
    lds_barrier();
    p ^= 1;
  }

  if (epi) {
    const float b0 = __logf(rh0) + rdp_h;
    const float b1 = __logf(rh1) + rdp_h;
    if (MODE == 0) {
      ws_b[c0 + lane] = b0;
      ws_b[c1 + lane] = b1;
    } else {
      post_b[c0 + lane] = a_h0 + b0 - ll;
      post_b[c1 + lane] = a_h1 + b1 - ll;
    }
  }
}

__global__ __launch_bounds__(512, 2)
void hmm_fwdbwd(const float* __restrict__ inputs, const float* __restrict__ log_A,
                const float* __restrict__ log_pi, const float* __restrict__ log_B,
                float* __restrict__ out, float* __restrict__ ws) {
  __shared__ Smem sm;
  if (blockIdx.x < B) fwd_impl(blockIdx.x, inputs, log_A, log_pi, log_B, out, sm);
  else                bwd_impl<0>(blockIdx.x - B, inputs, log_A, log_B, out, ws, sm);
}

__global__ __launch_bounds__(256)
void hmm_combine(const float* __restrict__ ws, float* __restrict__ out) {
  const size_t idx = (size_t)blockIdx.x * 256 + threadIdx.x;  // float4 index
  const int b = (int)(idx >> 17);  // L*Q/4 = 131072 float4 per batch
  const float ll = out[POST + b];
  float4 a = ((const float4*)out)[idx];
  const float4 be = ((const float4*)ws)[idx];
  a.x += be.x - ll;
  a.y += be.y - ll;
  a.z += be.z - ll;
  a.w += be.w - ll;
  ((float4*)out)[idx] = a;
}

__global__ __launch_bounds__(512, 2)
void hmm_fwd_only(const float* __restrict__ inputs, const float* __restrict__ log_A,
                  const float* __restrict__ log_pi, const float* __restrict__ log_B,
                  float* __restrict__ out) {
  __shared__ Smem sm;
  fwd_impl(blockIdx.x, inputs, log_A, log_pi, log_B, out, sm);
}

__global__ __launch_bounds__(512, 2)
void hmm_bwd_fused(const float* __restrict__ inputs, const float* __restrict__ log_A,
                   const float* __restrict__ log_B, float* __restrict__ out) {
  __shared__ Smem sm;
  bwd_impl<1>(blockIdx.x, inputs, log_A, log_B, out, nullptr, sm);
}

}  // namespace

extern "C" void kernel_launch(void* const* d_in, const int* in_sizes, int n_in,
                              void* d_out, int out_size, void* d_ws, size_t ws_size,
                              hipStream_t stream) {
  const float* inputs = (const float*)d_in[0];
  const float* log_A  = (const float*)d_in[1];
  const float* log_pi = (const float*)d_in[2];
  const float* log_B  = (const float*)d_in[3];
  float* out = (float*)d_out;
  float* ws  = (float*)d_ws;

  const size_t needA = POST * 6;  // beta f32 (4B) + e f16 (2B) per element
  const size_t needB = POST * sizeof(float);

  if (ws_size >= needA) {
    _Float16* eall = (_Float16*)(ws + POST);  // e region after beta region
    hipLaunchKernelGGL(hmm_emit, dim3(4 * B), dim3(512), 0, stream,
                       inputs, log_B, eall);
    hipLaunchKernelGGL(hmm_fwdbwd_e, dim3(2 * B), dim3(512), 0, stream,
                       eall, log_A, log_pi, out, ws);
    hipLaunchKernelGGL(hmm_combine, dim3((unsigned)(POST / 4 / 256)), dim3(256), 0,
                       stream, ws, out);
  } else if (ws_size >= needB) {
    hipLaunchKernelGGL(hmm_fwdbwd, dim3(2 * B), dim3(512), 0, stream,
                       inputs, log_A, log_pi, log_B, out, ws);
    hipLaunchKernelGGL(hmm_combine, dim3((unsigned)(POST / 4 / 256)), dim3(256), 0,
                       stream, ws, out);
  } else {
    hipLaunchKernelGGL(hmm_fwd_only, dim3(B), dim3(512), 0, stream,
                       inputs, log_A, log_pi, log_B, out);
    hipLaunchKernelGGL(hmm_bwd_fused, dim3(B), dim3(512), 0, stream,
                       inputs, log_A, log_B, out);
  }
}